// Round 12
// baseline (31.958 us; speedup 1.0000x reference)
//
#include <hip/hip_runtime.h>

#define BB 8
#define LL 2048
#define CC 64
#define NCH 32
#define SB 72   // bf16 LDS row stride (144 B): 16B-aligned, 2-way-free banks

typedef float f32x4 __attribute__((ext_vector_type(4)));
typedef short bf8 __attribute__((ext_vector_type(8)));

static __device__ __forceinline__ unsigned short f2b(float f) {
  unsigned u = __builtin_bit_cast(unsigned, f);
  u += 0x7fff + ((u >> 16) & 1);   // RNE (no NaN in this data)
  return (unsigned short)(u >> 16);
}
static __device__ __forceinline__ float b2f(unsigned short h) {
  return __builtin_bit_cast(float, ((unsigned)h) << 16);
}
#define MFMA(A, B, C) __builtin_amdgcn_mfma_f32_16x16x32_bf16(A, B, C, 0, 0, 0)

// ws layout: pref[BB*NCH*8192 ushort] | nu[BB*LL f32] | u[BB*LL f32] | w[BB*LL f32] | cnt[BB int]

// K1 (R9-exact + ticket reset): MFMA per-chunk partials PA=Vc^T Kc, PK=Kc^T Kc.
__global__ __launch_bounds__(512, 4) void k1_mfma(const float* __restrict__ k,
                                                  const float* __restrict__ v,
                                                  unsigned short* __restrict__ pref,
                                                  int* __restrict__ cnt) {
  __shared__ unsigned short sKcT[64 * SB], sVcT[64 * SB];
  int s = blockIdx.x >> 5, c = blockIdx.x & 31;
  int tid = threadIdx.x;
  if (c == 0 && tid == 0) cnt[s] = 0;   // visible to k3 via kernel boundary
  int tok0 = s * LL + c * CC;
  const float* kb = k + (size_t)tok0 * 64;
  const float* vb = v + (size_t)tok0 * 64;
  {
    int r = tid >> 3, cb = (tid & 7) * 8;
    f32x4 ka_ = *(const f32x4*)(kb + r * 64 + cb);
    f32x4 kb_ = *(const f32x4*)(kb + r * 64 + cb + 4);
    f32x4 va_ = *(const f32x4*)(vb + r * 64 + cb);
    f32x4 vb_ = *(const f32x4*)(vb + r * 64 + cb + 4);
    #pragma unroll
    for (int u = 0; u < 4; ++u) {
      sKcT[(cb + u) * SB + r] = f2b(ka_[u]);
      sKcT[(cb + 4 + u) * SB + r] = f2b(kb_[u]);
      sVcT[(cb + u) * SB + r] = f2b(va_[u]);
      sVcT[(cb + 4 + u) * SB + r] = f2b(vb_[u]);
    }
  }
  __syncthreads();
  int l = tid & 63, q = tid >> 6;
  int R0 = (q & 3) * 16, C0 = (q >> 2) * 32;
  int ar = R0 + (l & 15);
  int ko = (l >> 4) * 8;
#define LDA(T, ks) (*(const bf8*)&(T)[ar * SB + ko + (ks) * 32])
#define LDB(T, nt, ks) (*(const bf8*)&(T)[(C0 + 16 * (nt) + (l & 15)) * SB + ko + (ks) * 32])
  f32x4 PA[2] = {}, PK[2] = {};
  #pragma unroll
  for (int ks = 0; ks < 2; ++ks) {
    bf8 aV = LDA(sVcT, ks), aK = LDA(sKcT, ks);
    #pragma unroll
    for (int nt = 0; nt < 2; ++nt) {
      bf8 bK = LDB(sKcT, nt, ks);
      PA[nt] = MFMA(aV, bK, PA[nt]);
      PK[nt] = MFMA(aK, bK, PK[nt]);
    }
  }
  unsigned short* dst = pref + (size_t)(s * NCH + c) * 8192;
  #pragma unroll
  for (int nt = 0; nt < 2; ++nt)
    #pragma unroll
    for (int reg = 0; reg < 4; ++reg) {
      int row = R0 + (l >> 4) * 4 + reg;
      int col = C0 + 16 * nt + (l & 15);
      dst[row * 64 + col] = f2b(PA[nt][reg]);
      dst[4096 + row * 64 + col] = f2b(PK[nt][reg]);
    }
#undef LDA
#undef LDB
}

// K2 (R9-exact): exclusive prefix over 32 chunks, bf16 in/out, fp32 accumulate.
__global__ __launch_bounds__(256) void k2_prefix(unsigned short* __restrict__ pref) {
  int gid = blockIdx.x * 256 + threadIdx.x;   // [0, BB*8192)
  int s = gid >> 13, e = gid & 8191;
  unsigned short* base = pref + (size_t)s * NCH * 8192 + e;
  unsigned short x[16], y[16];
  #pragma unroll
  for (int u = 0; u < 16; ++u) x[u] = base[(size_t)u * 8192];
  #pragma unroll
  for (int u = 0; u < 16; ++u) y[u] = base[(size_t)(16 + u) * 8192];
  float acc = 0.f;
  #pragma unroll
  for (int u = 0; u < 16; ++u) {
    float t = b2f(x[u]);
    base[(size_t)u * 8192] = f2b(acc);
    acc += t;
  }
  #pragma unroll
  for (int u = 0; u < 16; ++u) {
    float t = b2f(y[u]);
    base[(size_t)(16 + u) * 8192] = f2b(acc);
    acc += t;
  }
}

// K3 (R9-exact + K4 ticket fold): MFMA chunk expansion; last-finished block
// per stream runs the prefix-and-output pass.
__global__ __launch_bounds__(512, 1) void k3_mfma(const float* __restrict__ k,
                                                  const float* __restrict__ v,
                                                  const unsigned short* __restrict__ pref,
                                                  float* __restrict__ uo,
                                                  float* __restrict__ wo,
                                                  float* __restrict__ nuo,
                                                  int* __restrict__ cnt,
                                                  float* __restrict__ out) {
  __shared__ unsigned short sKc[64 * SB], sVc[64 * SB], sA0[64 * SB],
                            sK0[64 * SB], sKcT[64 * SB], sVcT[64 * SB];
  __shared__ float sdK[64], sdN[64], comb[64][2][2];
  __shared__ int lastflag;
  unsigned short* sP = sK0;    // K0 dead after round A (barrier-guarded)
  unsigned short* sY = sVcT;   // VcT dead after round B (barrier-guarded)
  int s = blockIdx.x >> 5, c = blockIdx.x & 31;
  int tid = threadIdx.x;
  int tok0 = s * LL + c * CC;
  const float* kb = k + (size_t)tok0 * 64;
  const float* vb = v + (size_t)tok0 * 64;
  const unsigned short* gA0 = pref + (size_t)(s * NCH + c) * 8192;
  const unsigned short* gK0 = gA0 + 4096;

  // ---- stage: k/v fp32->bf16 (+transposes); A0/K0 raw bf16 copy
  {
    int r = tid >> 3, cb = (tid & 7) * 8;
    f32x4 ka_ = *(const f32x4*)(kb + r * 64 + cb);
    f32x4 kb_ = *(const f32x4*)(kb + r * 64 + cb + 4);
    f32x4 va_ = *(const f32x4*)(vb + r * 64 + cb);
    f32x4 vb_ = *(const f32x4*)(vb + r * 64 + cb + 4);
    bf8 wa = *(const bf8*)&gA0[r * 64 + cb];
    bf8 wq = *(const bf8*)&gK0[r * 64 + cb];
    bf8 wk, wv;
    #pragma unroll
    for (int u = 0; u < 4; ++u) {
      wk[u] = (short)f2b(ka_[u]); wk[4 + u] = (short)f2b(kb_[u]);
      wv[u] = (short)f2b(va_[u]); wv[4 + u] = (short)f2b(vb_[u]);
    }
    *(bf8*)&sKc[r * SB + cb] = wk;
    *(bf8*)&sVc[r * SB + cb] = wv;
    *(bf8*)&sA0[r * SB + cb] = wa;
    *(bf8*)&sK0[r * SB + cb] = wq;
    #pragma unroll
    for (int u = 0; u < 8; ++u) {
      sKcT[(cb + u) * SB + r] = (unsigned short)wk[u];
      sVcT[(cb + u) * SB + r] = (unsigned short)wv[u];
    }
  }
  __syncthreads();

  int l = tid & 63, q = tid >> 6;
  int R0 = (q & 3) * 16, C0 = (q >> 2) * 32, ch = q >> 2;
  int ar = R0 + (l & 15);
  int ko = (l >> 4) * 8;
#define LDA(T, ks) (*(const bf8*)&(T)[ar * SB + ko + (ks) * 32])
#define LDB(T, nt, ks) (*(const bf8*)&(T)[(C0 + 16 * (nt) + (l & 15)) * SB + ko + (ks) * 32])

  f32x4 X[2] = {}, Y[2] = {}, M[2] = {}, N[2] = {};
  #pragma unroll
  for (int ks = 0; ks < 2; ++ks) {
    bf8 aK = LDA(sKc, ks), aV = LDA(sVc, ks);
    #pragma unroll
    for (int nt = 0; nt < 2; ++nt) {
      M[nt] = MFMA(aK, LDB(sKc, nt, ks), M[nt]);
      N[nt] = MFMA(aV, LDB(sVc, nt, ks), N[nt]);
      X[nt] = MFMA(aK, LDB(sA0, nt, ks), X[nt]);
      Y[nt] = MFMA(aK, LDB(sK0, nt, ks), Y[nt]);
    }
  }
  __syncthreads();   // round-A reads of sK0 done before P overwrites it
  #pragma unroll
  for (int nt = 0; nt < 2; ++nt)
    #pragma unroll
    for (int reg = 0; reg < 4; ++reg) {
      int row = R0 + (l >> 4) * 4 + reg;
      int col = C0 + 16 * nt + (l & 15);
      float m = M[nt][reg];
      sP[row * SB + col] = (col < row) ? f2b(m) : (unsigned short)0;
      if (col == row) { sdK[row] = m; sdN[row] = N[nt][reg]; }
    }
  __syncthreads();
  #pragma unroll
  for (int ks = 0; ks < 2; ++ks) {
    bf8 aP = LDA(sP, ks);
    #pragma unroll
    for (int nt = 0; nt < 2; ++nt) {
      X[nt] = MFMA(aP, LDB(sVcT, nt, ks), X[nt]);
      Y[nt] = MFMA(aP, LDB(sKcT, nt, ks), Y[nt]);
    }
  }
  __syncthreads();   // round-B reads of sVcT done before Y overwrites it
  #pragma unroll
  for (int nt = 0; nt < 2; ++nt)
    #pragma unroll
    for (int reg = 0; reg < 4; ++reg) {
      int row = R0 + (l >> 4) * 4 + reg;
      int col = C0 + 16 * nt + (l & 15);
      sY[row * SB + col] = f2b(Y[nt][reg]);
    }
  __syncthreads();
  f32x4 Z[2] = {}, G[2] = {};
  #pragma unroll
  for (int ks = 0; ks < 2; ++ks) {
    bf8 aY = LDA(sY, ks);
    #pragma unroll
    for (int nt = 0; nt < 2; ++nt) {
      Z[nt] = MFMA(aY, LDB(sKc, nt, ks), Z[nt]);
      G[nt] = MFMA(aY, LDB(sA0, nt, ks), G[nt]);
    }
  }
  // ---- epilogue: per-row dots in D-layout (col=l&15, row=(l>>4)*4+reg)
  #pragma unroll
  for (int reg = 0; reg < 4; ++reg) {
    int row = R0 + (l >> 4) * 4 + reg;
    float ka = sdK[row], nv = sdN[row];
    float pu = 0.f, pw = 0.f;
    #pragma unroll
    for (int nt = 0; nt < 2; ++nt) {
      int col = C0 + 16 * nt + (l & 15);
      float x = X[nt][reg], y = Y[nt][reg], n = N[nt][reg];
      float z = Z[nt][reg], g = G[nt][reg];
      float vtl = b2f(sVc[row * SB + col]);
      float ktl = b2f(sKc[row * SB + col]);
      float zn = (col < row) ? z * n : 0.f;
      float vx = vtl * x;
      pu += 2.f * (vtl * g + zn) + x * x + 2.f * ka * vx + nv * (ktl * y);
      pw += vx;
    }
    #pragma unroll
    for (int mm = 1; mm < 16; mm <<= 1) {
      pu += __shfl_xor(pu, mm, 64);
      pw += __shfl_xor(pw, mm, 64);
    }
    if ((l & 15) == 0) { comb[row][ch][0] = pu; comb[row][ch][1] = pw; }
  }
  __syncthreads();
  if (tid < 64) {
    float ka = sdK[tid], nv = sdN[tid];
    float u = comb[tid][0][0] + comb[tid][1][0] + ka * ka * nv;
    float w = 2.f * (comb[tid][0][1] + comb[tid][1][1]) + ka * nv;
    uo[tok0 + tid] = u;
    wo[tok0 + tid] = w;
    nuo[tok0 + tid] = nv;
  }
#undef LDA
#undef LDB

  // ---- K4 fold: last-finished block of each stream runs the output pass
  __syncthreads();          // block writes drained (vmcnt(0) before barrier)
  if (tid == 0) {
    __threadfence();        // release
    int old = atomicAdd(&cnt[s], 1);
    lastflag = (old == NCH - 1) ? 1 : 0;
  }
  __syncthreads();
  if (!lastflag) return;
  __threadfence();          // acquire

  bool act = tid < 256;
  int wv = tid >> 6;
  __shared__ float su[4], sw[4], sn[4];
  const float* us = uo + s * LL;
  const float* wsp = wo + s * LL;
  const float* ns = nuo + s * LL;
  float pu[8], pw[8], pn[8];
  float tu = 0, tw = 0, tn = 0, iu = 0, iw = 0, in_ = 0;
  int base = tid * 8;
  if (act) {
    float ru = 0, rw = 0, rn = 0;
    #pragma unroll
    for (int e = 0; e < 8; ++e) {
      ru += us[base + e]; pu[e] = ru;
      rw += wsp[base + e]; pw[e] = rw;
      rn += ns[base + e]; pn[e] = rn;
    }
    tu = pu[7]; tw = pw[7]; tn = pn[7];
    iu = tu; iw = tw; in_ = tn;
    #pragma unroll
    for (int off = 1; off < 64; off <<= 1) {
      float a = __shfl_up(iu, off, 64);
      float b = __shfl_up(iw, off, 64);
      float c2 = __shfl_up(in_, off, 64);
      if (l >= off) { iu += a; iw += b; in_ += c2; }
    }
    if (l == 63) { su[wv] = iu; sw[wv] = iw; sn[wv] = in_; }
  }
  __syncthreads();
  if (act) {
    float bu = 0, bw = 0, bn = 0;
    for (int i2 = 0; i2 < wv; ++i2) { bu += su[i2]; bw += sw[i2]; bn += sn[i2]; }
    float eu = bu + iu - tu, ew = bw + iw - tw, en = bn + in_ - tn;
    float* os = out + s * LL;
    #pragma unroll
    for (int e = 0; e < 8; ++e) {
      int t = base + e;
      float inv = 1.0f / (float)(t + 1);
      float U = eu + pu[e], W = ew + pw[e], S = en + pn[e];
      os[t] = inv * (0.5f * S + inv * fmaf(0.5f * inv, U, -W));
    }
  }
}

extern "C" void kernel_launch(void* const* d_in, const int* in_sizes, int n_in,
                              void* d_out, int out_size, void* d_ws, size_t ws_size,
                              hipStream_t stream) {
  const float* k = (const float*)d_in[1];
  const float* v = (const float*)d_in[2];
  float* out = (float*)d_out;
  float* ws = (float*)d_ws;
  unsigned short* pref = (unsigned short*)ws;            // BB*NCH*8192 ushorts (4 MB)
  float* nu = ws + (size_t)BB * NCH * 4096;              // after pref (float units)
  float* uu = nu + BB * LL;
  float* ww = uu + BB * LL;
  int* cnt = (int*)(ww + BB * LL);
  hipLaunchKernelGGL(k1_mfma, dim3(BB * NCH), dim3(512), 0, stream, k, v, pref, cnt);
  hipLaunchKernelGGL(k2_prefix, dim3(BB * 8192 / 256), dim3(256), 0, stream, pref);
  hipLaunchKernelGGL(k3_mfma, dim3(BB * NCH), dim3(512), 0, stream, k, v, pref,
                     uu, ww, nu, cnt, out);
}

// Round 13
// 27.419 us; speedup vs baseline: 1.1656x; 1.1656x over previous
//
#include <hip/hip_runtime.h>

#define BB 8
#define LL 2048
#define CC 64
#define NCH 32
#define SB 72   // bf16 LDS row stride (144 B): 16B-aligned, 2-way-free banks

typedef float f32x4 __attribute__((ext_vector_type(4)));
typedef short bf8 __attribute__((ext_vector_type(8)));

static __device__ __forceinline__ unsigned short f2b(float f) {
  unsigned u = __builtin_bit_cast(unsigned, f);
  u += 0x7fff + ((u >> 16) & 1);   // RNE (no NaN in this data)
  return (unsigned short)(u >> 16);
}
static __device__ __forceinline__ float b2f(unsigned short h) {
  return __builtin_bit_cast(float, ((unsigned)h) << 16);
}
#define MFMA(A, B, C) __builtin_amdgcn_mfma_f32_16x16x32_bf16(A, B, C, 0, 0, 0)

// ws layout: pref[BB*NCH*8192 ushort] | nu[BB*LL f32] | u[BB*LL f32] | w[BB*LL f32]

// K1 (R9-exact): MFMA per-chunk partials PA=Vc^T Kc, PK=Kc^T Kc -> pref (bf16).
__global__ __launch_bounds__(512, 4) void k1_mfma(const float* __restrict__ k,
                                                  const float* __restrict__ v,
                                                  unsigned short* __restrict__ pref) {
  __shared__ unsigned short sKcT[64 * SB], sVcT[64 * SB];
  int s = blockIdx.x >> 5, c = blockIdx.x & 31;
  int tid = threadIdx.x;
  int tok0 = s * LL + c * CC;
  const float* kb = k + (size_t)tok0 * 64;
  const float* vb = v + (size_t)tok0 * 64;
  {
    int r = tid >> 3, cb = (tid & 7) * 8;
    f32x4 ka_ = *(const f32x4*)(kb + r * 64 + cb);
    f32x4 kb_ = *(const f32x4*)(kb + r * 64 + cb + 4);
    f32x4 va_ = *(const f32x4*)(vb + r * 64 + cb);
    f32x4 vb_ = *(const f32x4*)(vb + r * 64 + cb + 4);
    #pragma unroll
    for (int u = 0; u < 4; ++u) {
      sKcT[(cb + u) * SB + r] = f2b(ka_[u]);
      sKcT[(cb + 4 + u) * SB + r] = f2b(kb_[u]);
      sVcT[(cb + u) * SB + r] = f2b(va_[u]);
      sVcT[(cb + 4 + u) * SB + r] = f2b(vb_[u]);
    }
  }
  __syncthreads();
  int l = tid & 63, q = tid >> 6;
  int R0 = (q & 3) * 16, C0 = (q >> 2) * 32;
  int ar = R0 + (l & 15);
  int ko = (l >> 4) * 8;
#define LDA(T, ks) (*(const bf8*)&(T)[ar * SB + ko + (ks) * 32])
#define LDB(T, nt, ks) (*(const bf8*)&(T)[(C0 + 16 * (nt) + (l & 15)) * SB + ko + (ks) * 32])
  f32x4 PA[2] = {}, PK[2] = {};
  #pragma unroll
  for (int ks = 0; ks < 2; ++ks) {
    bf8 aV = LDA(sVcT, ks), aK = LDA(sKcT, ks);
    #pragma unroll
    for (int nt = 0; nt < 2; ++nt) {
      bf8 bK = LDB(sKcT, nt, ks);
      PA[nt] = MFMA(aV, bK, PA[nt]);
      PK[nt] = MFMA(aK, bK, PK[nt]);
    }
  }
  unsigned short* dst = pref + (size_t)(s * NCH + c) * 8192;
  #pragma unroll
  for (int nt = 0; nt < 2; ++nt)
    #pragma unroll
    for (int reg = 0; reg < 4; ++reg) {
      int row = R0 + (l >> 4) * 4 + reg;
      int col = C0 + 16 * nt + (l & 15);
      dst[row * 64 + col] = f2b(PA[nt][reg]);
      dst[4096 + row * 64 + col] = f2b(PK[nt][reg]);
    }
#undef LDA
#undef LDB
}

// K3: k2 folded in by dataflow — each block sums bf16 chunk-partials 0..c-1
// (f32 accumulate, L2/L3-resident reads) into its A0/K0 LDS tiles, then runs
// the R9-exact MFMA chunk expansion.
__global__ __launch_bounds__(512, 1) void k3_mfma(const float* __restrict__ k,
                                                  const float* __restrict__ v,
                                                  const unsigned short* __restrict__ pref,
                                                  float* __restrict__ uo,
                                                  float* __restrict__ wo,
                                                  float* __restrict__ nuo) {
  __shared__ unsigned short sKc[64 * SB], sVc[64 * SB], sA0[64 * SB],
                            sK0[64 * SB], sKcT[64 * SB], sVcT[64 * SB];
  __shared__ float sdK[64], sdN[64], comb[64][2][2];
  unsigned short* sP = sK0;    // K0 dead after round A (barrier-guarded)
  unsigned short* sY = sVcT;   // VcT dead after round B (barrier-guarded)
  int s = blockIdx.x >> 5, c = blockIdx.x & 31;
  int tid = threadIdx.x;
  int tok0 = s * LL + c * CC;
  const float* kb = k + (size_t)tok0 * 64;
  const float* vb = v + (size_t)tok0 * 64;
  const unsigned short* pstream = pref + (size_t)s * NCH * 8192;

  // ---- stage: k/v fp32->bf16 (+transposes); A0/K0 = f32 sum of partials 0..c-1
  {
    int r = tid >> 3, cb = (tid & 7) * 8;
    int eoff = r * 64 + cb;
    f32x4 ka_ = *(const f32x4*)(kb + eoff);
    f32x4 kb_ = *(const f32x4*)(kb + eoff + 4);
    f32x4 va_ = *(const f32x4*)(vb + eoff);
    f32x4 vb_ = *(const f32x4*)(vb + eoff + 4);
    float accA[8] = {}, accK[8] = {};
    {
      int cc = 0;
      for (; cc + 2 <= c; cc += 2) {
        bf8 pa0 = *(const bf8*)&pstream[(size_t)cc * 8192 + eoff];
        bf8 pk0 = *(const bf8*)&pstream[(size_t)cc * 8192 + 4096 + eoff];
        bf8 pa1 = *(const bf8*)&pstream[(size_t)(cc + 1) * 8192 + eoff];
        bf8 pk1 = *(const bf8*)&pstream[(size_t)(cc + 1) * 8192 + 4096 + eoff];
        #pragma unroll
        for (int u = 0; u < 8; ++u) {
          accA[u] += b2f((unsigned short)pa0[u]) + b2f((unsigned short)pa1[u]);
          accK[u] += b2f((unsigned short)pk0[u]) + b2f((unsigned short)pk1[u]);
        }
      }
      if (cc < c) {
        bf8 pa0 = *(const bf8*)&pstream[(size_t)cc * 8192 + eoff];
        bf8 pk0 = *(const bf8*)&pstream[(size_t)cc * 8192 + 4096 + eoff];
        #pragma unroll
        for (int u = 0; u < 8; ++u) {
          accA[u] += b2f((unsigned short)pa0[u]);
          accK[u] += b2f((unsigned short)pk0[u]);
        }
      }
    }
    bf8 wk, wv, wa, wq;
    #pragma unroll
    for (int u = 0; u < 4; ++u) {
      wk[u] = (short)f2b(ka_[u]); wk[4 + u] = (short)f2b(kb_[u]);
      wv[u] = (short)f2b(va_[u]); wv[4 + u] = (short)f2b(vb_[u]);
    }
    #pragma unroll
    for (int u = 0; u < 8; ++u) {
      wa[u] = (short)f2b(accA[u]);
      wq[u] = (short)f2b(accK[u]);
    }
    *(bf8*)&sKc[r * SB + cb] = wk;
    *(bf8*)&sVc[r * SB + cb] = wv;
    *(bf8*)&sA0[r * SB + cb] = wa;
    *(bf8*)&sK0[r * SB + cb] = wq;
    #pragma unroll
    for (int u = 0; u < 8; ++u) {
      sKcT[(cb + u) * SB + r] = (unsigned short)wk[u];
      sVcT[(cb + u) * SB + r] = (unsigned short)wv[u];
    }
  }
  __syncthreads();

  int l = tid & 63, q = tid >> 6;
  int R0 = (q & 3) * 16, C0 = (q >> 2) * 32, ch = q >> 2;
  int ar = R0 + (l & 15);
  int ko = (l >> 4) * 8;
#define LDA(T, ks) (*(const bf8*)&(T)[ar * SB + ko + (ks) * 32])
#define LDB(T, nt, ks) (*(const bf8*)&(T)[(C0 + 16 * (nt) + (l & 15)) * SB + ko + (ks) * 32])

  f32x4 X[2] = {}, Y[2] = {}, M[2] = {}, N[2] = {};
  #pragma unroll
  for (int ks = 0; ks < 2; ++ks) {
    bf8 aK = LDA(sKc, ks), aV = LDA(sVc, ks);
    #pragma unroll
    for (int nt = 0; nt < 2; ++nt) {
      M[nt] = MFMA(aK, LDB(sKc, nt, ks), M[nt]);
      N[nt] = MFMA(aV, LDB(sVc, nt, ks), N[nt]);
      X[nt] = MFMA(aK, LDB(sA0, nt, ks), X[nt]);
      Y[nt] = MFMA(aK, LDB(sK0, nt, ks), Y[nt]);
    }
  }
  __syncthreads();   // round-A reads of sK0 done before P overwrites it
  #pragma unroll
  for (int nt = 0; nt < 2; ++nt)
    #pragma unroll
    for (int reg = 0; reg < 4; ++reg) {
      int row = R0 + (l >> 4) * 4 + reg;
      int col = C0 + 16 * nt + (l & 15);
      float m = M[nt][reg];
      sP[row * SB + col] = (col < row) ? f2b(m) : (unsigned short)0;
      if (col == row) { sdK[row] = m; sdN[row] = N[nt][reg]; }
    }
  __syncthreads();
  #pragma unroll
  for (int ks = 0; ks < 2; ++ks) {
    bf8 aP = LDA(sP, ks);
    #pragma unroll
    for (int nt = 0; nt < 2; ++nt) {
      X[nt] = MFMA(aP, LDB(sVcT, nt, ks), X[nt]);
      Y[nt] = MFMA(aP, LDB(sKcT, nt, ks), Y[nt]);
    }
  }
  __syncthreads();   // round-B reads of sVcT done before Y overwrites it
  #pragma unroll
  for (int nt = 0; nt < 2; ++nt)
    #pragma unroll
    for (int reg = 0; reg < 4; ++reg) {
      int row = R0 + (l >> 4) * 4 + reg;
      int col = C0 + 16 * nt + (l & 15);
      sY[row * SB + col] = f2b(Y[nt][reg]);
    }
  __syncthreads();
  f32x4 Z[2] = {}, G[2] = {};
  #pragma unroll
  for (int ks = 0; ks < 2; ++ks) {
    bf8 aY = LDA(sY, ks);
    #pragma unroll
    for (int nt = 0; nt < 2; ++nt) {
      Z[nt] = MFMA(aY, LDB(sKc, nt, ks), Z[nt]);
      G[nt] = MFMA(aY, LDB(sA0, nt, ks), G[nt]);
    }
  }
  // ---- epilogue: per-row dots in D-layout (col=l&15, row=(l>>4)*4+reg)
  #pragma unroll
  for (int reg = 0; reg < 4; ++reg) {
    int row = R0 + (l >> 4) * 4 + reg;
    float ka = sdK[row], nv = sdN[row];
    float pu = 0.f, pw = 0.f;
    #pragma unroll
    for (int nt = 0; nt < 2; ++nt) {
      int col = C0 + 16 * nt + (l & 15);
      float x = X[nt][reg], y = Y[nt][reg], n = N[nt][reg];
      float z = Z[nt][reg], g = G[nt][reg];
      float vtl = b2f(sVc[row * SB + col]);
      float ktl = b2f(sKc[row * SB + col]);
      float zn = (col < row) ? z * n : 0.f;
      float vx = vtl * x;
      pu += 2.f * (vtl * g + zn) + x * x + 2.f * ka * vx + nv * (ktl * y);
      pw += vx;
    }
    #pragma unroll
    for (int mm = 1; mm < 16; mm <<= 1) {
      pu += __shfl_xor(pu, mm, 64);
      pw += __shfl_xor(pw, mm, 64);
    }
    if ((l & 15) == 0) { comb[row][ch][0] = pu; comb[row][ch][1] = pw; }
  }
  __syncthreads();
  if (tid < 64) {
    float ka = sdK[tid], nv = sdN[tid];
    float u = comb[tid][0][0] + comb[tid][1][0] + ka * ka * nv;
    float w = 2.f * (comb[tid][0][1] + comb[tid][1][1]) + ka * nv;
    uo[tok0 + tid] = u;
    wo[tok0 + tid] = w;
    nuo[tok0 + tid] = nv;
  }
#undef LDA
#undef LDB
}

// K4 (R9-exact): per-stream inclusive prefixes of u, w, nu -> out.
__global__ __launch_bounds__(256) void k4_out(const float* __restrict__ u,
                                              const float* __restrict__ w,
                                              const float* __restrict__ nu,
                                              float* __restrict__ out) {
  int s = blockIdx.x;
  int tid = threadIdx.x, l = tid & 63, wv = tid >> 6;
  __shared__ float su[4], sw[4], sn[4];
  const float* us = u + s * LL;
  const float* wsp = w + s * LL;
  const float* ns = nu + s * LL;
  float pu[8], pw[8], pn[8];
  int base = tid * 8;
  {
    float ru = 0, rw = 0, rn = 0;
    #pragma unroll
    for (int e = 0; e < 8; ++e) {
      ru += us[base + e]; pu[e] = ru;
      rw += wsp[base + e]; pw[e] = rw;
      rn += ns[base + e]; pn[e] = rn;
    }
  }
  float tu = pu[7], tw = pw[7], tn = pn[7];
  float iu = tu, iw = tw, in_ = tn;
  #pragma unroll
  for (int off = 1; off < 64; off <<= 1) {
    float a = __shfl_up(iu, off, 64);
    float b = __shfl_up(iw, off, 64);
    float c2 = __shfl_up(in_, off, 64);
    if (l >= off) { iu += a; iw += b; in_ += c2; }
  }
  if (l == 63) { su[wv] = iu; sw[wv] = iw; sn[wv] = in_; }
  __syncthreads();
  float bu = 0, bw = 0, bn = 0;
  for (int i2 = 0; i2 < wv; ++i2) { bu += su[i2]; bw += sw[i2]; bn += sn[i2]; }
  float eu = bu + iu - tu, ew = bw + iw - tw, en = bn + in_ - tn;
  float* os = out + s * LL;
  #pragma unroll
  for (int e = 0; e < 8; ++e) {
    int t = base + e;
    float inv = 1.0f / (float)(t + 1);
    float U = eu + pu[e], W = ew + pw[e], S = en + pn[e];
    os[t] = inv * (0.5f * S + inv * fmaf(0.5f * inv, U, -W));
  }
}

extern "C" void kernel_launch(void* const* d_in, const int* in_sizes, int n_in,
                              void* d_out, int out_size, void* d_ws, size_t ws_size,
                              hipStream_t stream) {
  const float* k = (const float*)d_in[1];
  const float* v = (const float*)d_in[2];
  float* out = (float*)d_out;
  float* ws = (float*)d_ws;
  unsigned short* pref = (unsigned short*)ws;            // BB*NCH*8192 ushorts (4 MB)
  float* nu = ws + (size_t)BB * NCH * 4096;              // after pref (float units)
  float* uu = nu + BB * LL;
  float* ww = uu + BB * LL;
  hipLaunchKernelGGL(k1_mfma, dim3(BB * NCH), dim3(512), 0, stream, k, v, pref);
  hipLaunchKernelGGL(k3_mfma, dim3(BB * NCH), dim3(512), 0, stream, k, v, pref,
                     uu, ww, nu);
  hipLaunchKernelGGL(k4_out, dim3(BB), dim3(256), 0, stream, uu, ww, nu, out);
}

// Round 14
// 23.733 us; speedup vs baseline: 1.3466x; 1.1553x over previous
//
#include <hip/hip_runtime.h>

#define BB 8
#define LL 2048
#define CC 64
#define NCH 32
#define SB 72   // bf16 LDS row stride (144 B): 16B-aligned, 2-way-free banks

typedef float f32x4 __attribute__((ext_vector_type(4)));
typedef short bf8 __attribute__((ext_vector_type(8)));
typedef unsigned short us4 __attribute__((ext_vector_type(4)));

static __device__ __forceinline__ unsigned short f2b(float f) {
  unsigned u = __builtin_bit_cast(unsigned, f);
  u += 0x7fff + ((u >> 16) & 1);   // RNE (no NaN in this data)
  return (unsigned short)(u >> 16);
}
static __device__ __forceinline__ float b2f(unsigned short h) {
  return __builtin_bit_cast(float, ((unsigned)h) << 16);
}
#define MFMA(A, B, C) __builtin_amdgcn_mfma_f32_16x16x32_bf16(A, B, C, 0, 0, 0)

// ws layout: pref[BB*NCH*8192 ushort] | nu[BB*LL f32] | u[BB*LL f32] | w[BB*LL f32]

// K1 (R9-exact): MFMA per-chunk partials PA=Vc^T Kc, PK=Kc^T Kc -> pref (bf16).
__global__ __launch_bounds__(512, 4) void k1_mfma(const float* __restrict__ k,
                                                  const float* __restrict__ v,
                                                  unsigned short* __restrict__ pref) {
  __shared__ unsigned short sKcT[64 * SB], sVcT[64 * SB];
  int s = blockIdx.x >> 5, c = blockIdx.x & 31;
  int tid = threadIdx.x;
  int tok0 = s * LL + c * CC;
  const float* kb = k + (size_t)tok0 * 64;
  const float* vb = v + (size_t)tok0 * 64;
  {
    int r = tid >> 3, cb = (tid & 7) * 8;
    f32x4 ka_ = *(const f32x4*)(kb + r * 64 + cb);
    f32x4 kb_ = *(const f32x4*)(kb + r * 64 + cb + 4);
    f32x4 va_ = *(const f32x4*)(vb + r * 64 + cb);
    f32x4 vb_ = *(const f32x4*)(vb + r * 64 + cb + 4);
    #pragma unroll
    for (int u = 0; u < 4; ++u) {
      sKcT[(cb + u) * SB + r] = f2b(ka_[u]);
      sKcT[(cb + 4 + u) * SB + r] = f2b(kb_[u]);
      sVcT[(cb + u) * SB + r] = f2b(va_[u]);
      sVcT[(cb + 4 + u) * SB + r] = f2b(vb_[u]);
    }
  }
  __syncthreads();
  int l = tid & 63, q = tid >> 6;
  int R0 = (q & 3) * 16, C0 = (q >> 2) * 32;
  int ar = R0 + (l & 15);
  int ko = (l >> 4) * 8;
#define LDA(T, ks) (*(const bf8*)&(T)[ar * SB + ko + (ks) * 32])
#define LDB(T, nt, ks) (*(const bf8*)&(T)[(C0 + 16 * (nt) + (l & 15)) * SB + ko + (ks) * 32])
  f32x4 PA[2] = {}, PK[2] = {};
  #pragma unroll
  for (int ks = 0; ks < 2; ++ks) {
    bf8 aV = LDA(sVcT, ks), aK = LDA(sKcT, ks);
    #pragma unroll
    for (int nt = 0; nt < 2; ++nt) {
      bf8 bK = LDB(sKcT, nt, ks);
      PA[nt] = MFMA(aV, bK, PA[nt]);
      PK[nt] = MFMA(aK, bK, PK[nt]);
    }
  }
  unsigned short* dst = pref + (size_t)(s * NCH + c) * 8192;
  #pragma unroll
  for (int nt = 0; nt < 2; ++nt)
    #pragma unroll
    for (int reg = 0; reg < 4; ++reg) {
      int row = R0 + (l >> 4) * 4 + reg;
      int col = C0 + 16 * nt + (l & 15);
      dst[row * 64 + col] = f2b(PA[nt][reg]);
      dst[4096 + row * 64 + col] = f2b(PK[nt][reg]);
    }
#undef LDA
#undef LDB
}

// K2: exclusive prefix over 32 chunks; ushort4-wide chains (512 B/wave-instr),
// 16-deep load batching keeps ~2 MB in flight. Chains independent -> numerics
// identical to the scalar version.
__global__ __launch_bounds__(256) void k2_prefix(unsigned short* __restrict__ pref) {
  int gid = blockIdx.x * 256 + threadIdx.x;   // [0, BB*2048)
  int s = gid >> 11;
  int e = (gid & 2047) * 4;
  unsigned short* base = pref + (size_t)s * NCH * 8192 + e;
  us4 x[16], y[16];
  #pragma unroll
  for (int u = 0; u < 16; ++u) x[u] = *(const us4*)&base[(size_t)u * 8192];
  #pragma unroll
  for (int u = 0; u < 16; ++u) y[u] = *(const us4*)&base[(size_t)(16 + u) * 8192];
  float a0 = 0.f, a1 = 0.f, a2 = 0.f, a3 = 0.f;
  #pragma unroll
  for (int u = 0; u < 16; ++u) {
    us4 t = x[u];
    us4 o = {f2b(a0), f2b(a1), f2b(a2), f2b(a3)};
    *(us4*)&base[(size_t)u * 8192] = o;
    a0 += b2f(t[0]); a1 += b2f(t[1]); a2 += b2f(t[2]); a3 += b2f(t[3]);
  }
  #pragma unroll
  for (int u = 0; u < 16; ++u) {
    us4 t = y[u];
    us4 o = {f2b(a0), f2b(a1), f2b(a2), f2b(a3)};
    *(us4*)&base[(size_t)(16 + u) * 8192] = o;
    a0 += b2f(t[0]); a1 += b2f(t[1]); a2 += b2f(t[2]); a3 += b2f(t[3]);
  }
}

// K3 (R9-exact): MFMA chunk expansion; emits u, w, nu per token.
__global__ __launch_bounds__(512, 1) void k3_mfma(const float* __restrict__ k,
                                                  const float* __restrict__ v,
                                                  const unsigned short* __restrict__ pref,
                                                  float* __restrict__ uo,
                                                  float* __restrict__ wo,
                                                  float* __restrict__ nuo) {
  __shared__ unsigned short sKc[64 * SB], sVc[64 * SB], sA0[64 * SB],
                            sK0[64 * SB], sKcT[64 * SB], sVcT[64 * SB];
  __shared__ float sdK[64], sdN[64], comb[64][2][2];
  unsigned short* sP = sK0;    // K0 dead after round A (barrier-guarded)
  unsigned short* sY = sVcT;   // VcT dead after round B (barrier-guarded)
  int s = blockIdx.x >> 5, c = blockIdx.x & 31;
  int tid = threadIdx.x;
  int tok0 = s * LL + c * CC;
  const float* kb = k + (size_t)tok0 * 64;
  const float* vb = v + (size_t)tok0 * 64;
  const unsigned short* gA0 = pref + (size_t)(s * NCH + c) * 8192;
  const unsigned short* gK0 = gA0 + 4096;

  {
    int r = tid >> 3, cb = (tid & 7) * 8;
    f32x4 ka_ = *(const f32x4*)(kb + r * 64 + cb);
    f32x4 kb_ = *(const f32x4*)(kb + r * 64 + cb + 4);
    f32x4 va_ = *(const f32x4*)(vb + r * 64 + cb);
    f32x4 vb_ = *(const f32x4*)(vb + r * 64 + cb + 4);
    bf8 wa = *(const bf8*)&gA0[r * 64 + cb];
    bf8 wq = *(const bf8*)&gK0[r * 64 + cb];
    bf8 wk, wv;
    #pragma unroll
    for (int u = 0; u < 4; ++u) {
      wk[u] = (short)f2b(ka_[u]); wk[4 + u] = (short)f2b(kb_[u]);
      wv[u] = (short)f2b(va_[u]); wv[4 + u] = (short)f2b(vb_[u]);
    }
    *(bf8*)&sKc[r * SB + cb] = wk;
    *(bf8*)&sVc[r * SB + cb] = wv;
    *(bf8*)&sA0[r * SB + cb] = wa;
    *(bf8*)&sK0[r * SB + cb] = wq;
    #pragma unroll
    for (int u = 0; u < 8; ++u) {
      sKcT[(cb + u) * SB + r] = (unsigned short)wk[u];
      sVcT[(cb + u) * SB + r] = (unsigned short)wv[u];
    }
  }
  __syncthreads();

  int l = tid & 63, q = tid >> 6;
  int R0 = (q & 3) * 16, C0 = (q >> 2) * 32, ch = q >> 2;
  int ar = R0 + (l & 15);
  int ko = (l >> 4) * 8;
#define LDA(T, ks) (*(const bf8*)&(T)[ar * SB + ko + (ks) * 32])
#define LDB(T, nt, ks) (*(const bf8*)&(T)[(C0 + 16 * (nt) + (l & 15)) * SB + ko + (ks) * 32])

  f32x4 X[2] = {}, Y[2] = {}, M[2] = {}, N[2] = {};
  #pragma unroll
  for (int ks = 0; ks < 2; ++ks) {
    bf8 aK = LDA(sKc, ks), aV = LDA(sVc, ks);
    #pragma unroll
    for (int nt = 0; nt < 2; ++nt) {
      M[nt] = MFMA(aK, LDB(sKc, nt, ks), M[nt]);
      N[nt] = MFMA(aV, LDB(sVc, nt, ks), N[nt]);
      X[nt] = MFMA(aK, LDB(sA0, nt, ks), X[nt]);
      Y[nt] = MFMA(aK, LDB(sK0, nt, ks), Y[nt]);
    }
  }
  __syncthreads();
  #pragma unroll
  for (int nt = 0; nt < 2; ++nt)
    #pragma unroll
    for (int reg = 0; reg < 4; ++reg) {
      int row = R0 + (l >> 4) * 4 + reg;
      int col = C0 + 16 * nt + (l & 15);
      float m = M[nt][reg];
      sP[row * SB + col] = (col < row) ? f2b(m) : (unsigned short)0;
      if (col == row) { sdK[row] = m; sdN[row] = N[nt][reg]; }
    }
  __syncthreads();
  #pragma unroll
  for (int ks = 0; ks < 2; ++ks) {
    bf8 aP = LDA(sP, ks);
    #pragma unroll
    for (int nt = 0; nt < 2; ++nt) {
      X[nt] = MFMA(aP, LDB(sVcT, nt, ks), X[nt]);
      Y[nt] = MFMA(aP, LDB(sKcT, nt, ks), Y[nt]);
    }
  }
  __syncthreads();
  #pragma unroll
  for (int nt = 0; nt < 2; ++nt)
    #pragma unroll
    for (int reg = 0; reg < 4; ++reg) {
      int row = R0 + (l >> 4) * 4 + reg;
      int col = C0 + 16 * nt + (l & 15);
      sY[row * SB + col] = f2b(Y[nt][reg]);
    }
  __syncthreads();
  f32x4 Z[2] = {}, G[2] = {};
  #pragma unroll
  for (int ks = 0; ks < 2; ++ks) {
    bf8 aY = LDA(sY, ks);
    #pragma unroll
    for (int nt = 0; nt < 2; ++nt) {
      Z[nt] = MFMA(aY, LDB(sKc, nt, ks), Z[nt]);
      G[nt] = MFMA(aY, LDB(sA0, nt, ks), G[nt]);
    }
  }
  #pragma unroll
  for (int reg = 0; reg < 4; ++reg) {
    int row = R0 + (l >> 4) * 4 + reg;
    float ka = sdK[row], nv = sdN[row];
    float pu = 0.f, pw = 0.f;
    #pragma unroll
    for (int nt = 0; nt < 2; ++nt) {
      int col = C0 + 16 * nt + (l & 15);
      float x = X[nt][reg], y = Y[nt][reg], n = N[nt][reg];
      float z = Z[nt][reg], g = G[nt][reg];
      float vtl = b2f(sVc[row * SB + col]);
      float ktl = b2f(sKc[row * SB + col]);
      float zn = (col < row) ? z * n : 0.f;
      float vx = vtl * x;
      pu += 2.f * (vtl * g + zn) + x * x + 2.f * ka * vx + nv * (ktl * y);
      pw += vx;
    }
    #pragma unroll
    for (int mm = 1; mm < 16; mm <<= 1) {
      pu += __shfl_xor(pu, mm, 64);
      pw += __shfl_xor(pw, mm, 64);
    }
    if ((l & 15) == 0) { comb[row][ch][0] = pu; comb[row][ch][1] = pw; }
  }
  __syncthreads();
  if (tid < 64) {
    float ka = sdK[tid], nv = sdN[tid];
    float u = comb[tid][0][0] + comb[tid][1][0] + ka * ka * nv;
    float w = 2.f * (comb[tid][0][1] + comb[tid][1][1]) + ka * nv;
    uo[tok0 + tid] = u;
    wo[tok0 + tid] = w;
    nuo[tok0 + tid] = nv;
  }
#undef LDA
#undef LDB
}

// K4 (R9-exact): per-stream inclusive prefixes of u, w, nu -> out.
__global__ __launch_bounds__(256) void k4_out(const float* __restrict__ u,
                                              const float* __restrict__ w,
                                              const float* __restrict__ nu,
                                              float* __restrict__ out) {
  int s = blockIdx.x;
  int tid = threadIdx.x, l = tid & 63, wv = tid >> 6;
  __shared__ float su[4], sw[4], sn[4];
  const float* us = u + s * LL;
  const float* wsp = w + s * LL;
  const float* ns = nu + s * LL;
  float pu[8], pw[8], pn[8];
  int base = tid * 8;
  {
    float ru = 0, rw = 0, rn = 0;
    #pragma unroll
    for (int e = 0; e < 8; ++e) {
      ru += us[base + e]; pu[e] = ru;
      rw += wsp[base + e]; pw[e] = rw;
      rn += ns[base + e]; pn[e] = rn;
    }
  }
  float tu = pu[7], tw = pw[7], tn = pn[7];
  float iu = tu, iw = tw, in_ = tn;
  #pragma unroll
  for (int off = 1; off < 64; off <<= 1) {
    float a = __shfl_up(iu, off, 64);
    float b = __shfl_up(iw, off, 64);
    float c2 = __shfl_up(in_, off, 64);
    if (l >= off) { iu += a; iw += b; in_ += c2; }
  }
  if (l == 63) { su[wv] = iu; sw[wv] = iw; sn[wv] = in_; }
  __syncthreads();
  float bu = 0, bw = 0, bn = 0;
  for (int i2 = 0; i2 < wv; ++i2) { bu += su[i2]; bw += sw[i2]; bn += sn[i2]; }
  float eu = bu + iu - tu, ew = bw + iw - tw, en = bn + in_ - tn;
  float* os = out + s * LL;
  #pragma unroll
  for (int e = 0; e < 8; ++e) {
    int t = base + e;
    float inv = 1.0f / (float)(t + 1);
    float U = eu + pu[e], W = ew + pw[e], S = en + pn[e];
    os[t] = inv * (0.5f * S + inv * fmaf(0.5f * inv, U, -W));
  }
}

extern "C" void kernel_launch(void* const* d_in, const int* in_sizes, int n_in,
                              void* d_out, int out_size, void* d_ws, size_t ws_size,
                              hipStream_t stream) {
  const float* k = (const float*)d_in[1];
  const float* v = (const float*)d_in[2];
  float* out = (float*)d_out;
  float* ws = (float*)d_ws;
  unsigned short* pref = (unsigned short*)ws;            // BB*NCH*8192 ushorts (4 MB)
  float* nu = ws + (size_t)BB * NCH * 4096;              // after pref (float units)
  float* uu = nu + BB * LL;
  float* ww = uu + BB * LL;
  hipLaunchKernelGGL(k1_mfma, dim3(BB * NCH), dim3(512), 0, stream, k, v, pref);
  hipLaunchKernelGGL(k2_prefix, dim3(BB * 2048 / 256), dim3(256), 0, stream, pref);
  hipLaunchKernelGGL(k3_mfma, dim3(BB * NCH), dim3(512), 0, stream, k, v, pref,
                     uu, ww, nu);
  hipLaunchKernelGGL(k4_out, dim3(BB), dim3(256), 0, stream, uu, ww, nu, out);
}

// Round 15
// 23.031 us; speedup vs baseline: 1.3876x; 1.0305x over previous
//
#include <hip/hip_runtime.h>

#define BB 8
#define LL 2048
#define CC 64
#define NCH 32
#define SB 72   // bf16 LDS row stride (144 B = 9 x 16B: keeps bf8 reads aligned)

typedef float f32x4 __attribute__((ext_vector_type(4)));
typedef short bf8 __attribute__((ext_vector_type(8)));

static __device__ __forceinline__ unsigned short f2b(float f) {
  unsigned u = __builtin_bit_cast(unsigned, f);
  u += 0x7fff + ((u >> 16) & 1);   // RNE (no NaN in this data)
  return (unsigned short)(u >> 16);
}
static __device__ __forceinline__ float b2f(unsigned short h) {
  return __builtin_bit_cast(float, ((unsigned)h) << 16);
}
#define MFMA(A, B, C) __builtin_amdgcn_mfma_f32_16x16x32_bf16(A, B, C, 0, 0, 0)

// ws layout: pref[BB*NCH*8192 ushort] | nu[BB*LL f32] | u[BB*LL f32] | w[BB*LL f32]

// K1: MFMA per-chunk partials. PA[i][j]=sum_t Vc[t][i]Kc[t][j], PK=Kc^T Kc.
__global__ __launch_bounds__(512, 4) void k1_mfma(const float* __restrict__ k,
                                                  const float* __restrict__ v,
                                                  unsigned short* __restrict__ pref) {
  __shared__ unsigned short sKcT[64 * SB], sVcT[64 * SB];
  int s = blockIdx.x >> 5, c = blockIdx.x & 31;
  int tid = threadIdx.x;
  int tok0 = s * LL + c * CC;
  const float* kb = k + (size_t)tok0 * 64;
  const float* vb = v + (size_t)tok0 * 64;
  {
    int r = tid >> 3, cb = (tid & 7) * 8;
    f32x4 ka_ = *(const f32x4*)(kb + r * 64 + cb);
    f32x4 kb_ = *(const f32x4*)(kb + r * 64 + cb + 4);
    f32x4 va_ = *(const f32x4*)(vb + r * 64 + cb);
    f32x4 vb_ = *(const f32x4*)(vb + r * 64 + cb + 4);
    #pragma unroll
    for (int u = 0; u < 4; ++u) {
      sKcT[(cb + u) * SB + r] = f2b(ka_[u]);
      sKcT[(cb + 4 + u) * SB + r] = f2b(kb_[u]);
      sVcT[(cb + u) * SB + r] = f2b(va_[u]);
      sVcT[(cb + 4 + u) * SB + r] = f2b(vb_[u]);
    }
  }
  __syncthreads();
  int l = tid & 63, q = tid >> 6;
  int R0 = (q & 3) * 16, C0 = (q >> 2) * 32;
  int ar = R0 + (l & 15);
  int ko = (l >> 4) * 8;
#define LDA(T, ks) (*(const bf8*)&(T)[ar * SB + ko + (ks) * 32])
#define LDB(T, nt, ks) (*(const bf8*)&(T)[(C0 + 16 * (nt) + (l & 15)) * SB + ko + (ks) * 32])
  f32x4 PA[2] = {}, PK[2] = {};
  #pragma unroll
  for (int ks = 0; ks < 2; ++ks) {
    bf8 aV = LDA(sVcT, ks), aK = LDA(sKcT, ks);
    #pragma unroll
    for (int nt = 0; nt < 2; ++nt) {
      bf8 bK = LDB(sKcT, nt, ks);
      PA[nt] = MFMA(aV, bK, PA[nt]);
      PK[nt] = MFMA(aK, bK, PK[nt]);
    }
  }
  unsigned short* dst = pref + (size_t)(s * NCH + c) * 8192;
  #pragma unroll
  for (int nt = 0; nt < 2; ++nt)
    #pragma unroll
    for (int reg = 0; reg < 4; ++reg) {
      int row = R0 + (l >> 4) * 4 + reg;
      int col = C0 + 16 * nt + (l & 15);
      dst[row * 64 + col] = f2b(PA[nt][reg]);
      dst[4096 + row * 64 + col] = f2b(PK[nt][reg]);
    }
#undef LDA
#undef LDB
}

// K2: exclusive prefix over 32 chunks, bf16 in/out, fp32 accumulate.
__global__ __launch_bounds__(256) void k2_prefix(unsigned short* __restrict__ pref) {
  int gid = blockIdx.x * 256 + threadIdx.x;   // [0, BB*8192)
  int s = gid >> 13, e = gid & 8191;
  unsigned short* base = pref + (size_t)s * NCH * 8192 + e;
  unsigned short x[16], y[16];
  #pragma unroll
  for (int u = 0; u < 16; ++u) x[u] = base[(size_t)u * 8192];
  #pragma unroll
  for (int u = 0; u < 16; ++u) y[u] = base[(size_t)(16 + u) * 8192];
  float acc = 0.f;
  #pragma unroll
  for (int u = 0; u < 16; ++u) {
    float t = b2f(x[u]);
    base[(size_t)u * 8192] = f2b(acc);
    acc += t;
  }
  #pragma unroll
  for (int u = 0; u < 16; ++u) {
    float t = b2f(y[u]);
    base[(size_t)(16 + u) * 8192] = f2b(acc);
    acc += t;
  }
}

// K3: MFMA chunk expansion; emits u, w, nu per token.
__global__ __launch_bounds__(512, 1) void k3_mfma(const float* __restrict__ k,
                                                  const float* __restrict__ v,
                                                  const unsigned short* __restrict__ pref,
                                                  float* __restrict__ uo,
                                                  float* __restrict__ wo,
                                                  float* __restrict__ nuo) {
  __shared__ unsigned short sKc[64 * SB], sVc[64 * SB], sA0[64 * SB],
                            sK0[64 * SB], sKcT[64 * SB], sVcT[64 * SB];
  __shared__ float sdK[64], sdN[64], comb[64][2][2];
  unsigned short* sP = sK0;    // K0 dead after round A (barrier-guarded)
  unsigned short* sY = sVcT;   // VcT dead after round B (barrier-guarded)
  int s = blockIdx.x >> 5, c = blockIdx.x & 31;
  int tid = threadIdx.x;
  int tok0 = s * LL + c * CC;
  const float* kb = k + (size_t)tok0 * 64;
  const float* vb = v + (size_t)tok0 * 64;
  const unsigned short* gA0 = pref + (size_t)(s * NCH + c) * 8192;
  const unsigned short* gK0 = gA0 + 4096;

  // ---- stage: k/v fp32->bf16 (+transposes); A0/K0 raw bf16 copy
  {
    int r = tid >> 3, cb = (tid & 7) * 8;
    f32x4 ka_ = *(const f32x4*)(kb + r * 64 + cb);
    f32x4 kb_ = *(const f32x4*)(kb + r * 64 + cb + 4);
    f32x4 va_ = *(const f32x4*)(vb + r * 64 + cb);
    f32x4 vb_ = *(const f32x4*)(vb + r * 64 + cb + 4);
    bf8 wa = *(const bf8*)&gA0[r * 64 + cb];
    bf8 wq = *(const bf8*)&gK0[r * 64 + cb];
    bf8 wk, wv;
    #pragma unroll
    for (int u = 0; u < 4; ++u) {
      wk[u] = (short)f2b(ka_[u]); wk[4 + u] = (short)f2b(kb_[u]);
      wv[u] = (short)f2b(va_[u]); wv[4 + u] = (short)f2b(vb_[u]);
    }
    *(bf8*)&sKc[r * SB + cb] = wk;
    *(bf8*)&sVc[r * SB + cb] = wv;
    *(bf8*)&sA0[r * SB + cb] = wa;
    *(bf8*)&sK0[r * SB + cb] = wq;
    #pragma unroll
    for (int u = 0; u < 8; ++u) {
      sKcT[(cb + u) * SB + r] = (unsigned short)wk[u];
      sVcT[(cb + u) * SB + r] = (unsigned short)wv[u];
    }
  }
  __syncthreads();

  int l = tid & 63, q = tid >> 6;
  int R0 = (q & 3) * 16, C0 = (q >> 2) * 32, ch = q >> 2;
  int ar = R0 + (l & 15);
  int ko = (l >> 4) * 8;
#define LDA(T, ks) (*(const bf8*)&(T)[ar * SB + ko + (ks) * 32])
#define LDB(T, nt, ks) (*(const bf8*)&(T)[(C0 + 16 * (nt) + (l & 15)) * SB + ko + (ks) * 32])

  f32x4 X[2] = {}, Y[2] = {}, M[2] = {}, N[2] = {};
  #pragma unroll
  for (int ks = 0; ks < 2; ++ks) {
    bf8 aK = LDA(sKc, ks), aV = LDA(sVc, ks);
    #pragma unroll
    for (int nt = 0; nt < 2; ++nt) {
      M[nt] = MFMA(aK, LDB(sKc, nt, ks), M[nt]);
      N[nt] = MFMA(aV, LDB(sVc, nt, ks), N[nt]);
      X[nt] = MFMA(aK, LDB(sA0, nt, ks), X[nt]);
      Y[nt] = MFMA(aK, LDB(sK0, nt, ks), Y[nt]);
    }
  }
  __syncthreads();   // round-A reads of sK0 done before P overwrites it
  #pragma unroll
  for (int nt = 0; nt < 2; ++nt)
    #pragma unroll
    for (int reg = 0; reg < 4; ++reg) {
      int row = R0 + (l >> 4) * 4 + reg;
      int col = C0 + 16 * nt + (l & 15);
      float m = M[nt][reg];
      sP[row * SB + col] = (col < row) ? f2b(m) : (unsigned short)0;
      if (col == row) { sdK[row] = m; sdN[row] = N[nt][reg]; }
    }
  __syncthreads();
  #pragma unroll
  for (int ks = 0; ks < 2; ++ks) {
    bf8 aP = LDA(sP, ks);
    #pragma unroll
    for (int nt = 0; nt < 2; ++nt) {
      X[nt] = MFMA(aP, LDB(sVcT, nt, ks), X[nt]);
      Y[nt] = MFMA(aP, LDB(sKcT, nt, ks), Y[nt]);
    }
  }
  __syncthreads();   // round-B reads of sVcT done before Y overwrites it
  #pragma unroll
  for (int nt = 0; nt < 2; ++nt)
    #pragma unroll
    for (int reg = 0; reg < 4; ++reg) {
      int row = R0 + (l >> 4) * 4 + reg;
      int col = C0 + 16 * nt + (l & 15);
      sY[row * SB + col] = f2b(Y[nt][reg]);
    }
  __syncthreads();
  f32x4 Z[2] = {}, G[2] = {};
  #pragma unroll
  for (int ks = 0; ks < 2; ++ks) {
    bf8 aY = LDA(sY, ks);
    #pragma unroll
    for (int nt = 0; nt < 2; ++nt) {
      Z[nt] = MFMA(aY, LDB(sKc, nt, ks), Z[nt]);
      G[nt] = MFMA(aY, LDB(sA0, nt, ks), G[nt]);
    }
  }
  // ---- epilogue: per-row dots in D-layout (col=l&15, row=(l>>4)*4+reg)
  #pragma unroll
  for (int reg = 0; reg < 4; ++reg) {
    int row = R0 + (l >> 4) * 4 + reg;
    float ka = sdK[row], nv = sdN[row];
    float pu = 0.f, pw = 0.f;
    #pragma unroll
    for (int nt = 0; nt < 2; ++nt) {
      int col = C0 + 16 * nt + (l & 15);
      float x = X[nt][reg], y = Y[nt][reg], n = N[nt][reg];
      float z = Z[nt][reg], g = G[nt][reg];
      float vtl = b2f(sVc[row * SB + col]);
      float ktl = b2f(sKc[row * SB + col]);
      float zn = (col < row) ? z * n : 0.f;
      float vx = vtl * x;
      pu += 2.f * (vtl * g + zn) + x * x + 2.f * ka * vx + nv * (ktl * y);
      pw += vx;
    }
    #pragma unroll
    for (int mm = 1; mm < 16; mm <<= 1) {
      pu += __shfl_xor(pu, mm, 64);
      pw += __shfl_xor(pw, mm, 64);
    }
    if ((l & 15) == 0) { comb[row][ch][0] = pu; comb[row][ch][1] = pw; }
  }
  __syncthreads();
  if (tid < 64) {
    float ka = sdK[tid], nv = sdN[tid];
    float u = comb[tid][0][0] + comb[tid][1][0] + ka * ka * nv;
    float w = 2.f * (comb[tid][0][1] + comb[tid][1][1]) + ka * nv;
    uo[tok0 + tid] = u;
    wo[tok0 + tid] = w;
    nuo[tok0 + tid] = nv;
  }
#undef LDA
#undef LDB
}

// K4: per-stream inclusive prefixes of u, w, nu -> out.
__global__ __launch_bounds__(256) void k4_out(const float* __restrict__ u,
                                              const float* __restrict__ w,
                                              const float* __restrict__ nu,
                                              float* __restrict__ out) {
  int s = blockIdx.x;
  int tid = threadIdx.x, l = tid & 63, wv = tid >> 6;
  __shared__ float su[4], sw[4], sn[4];
  const float* us = u + s * LL;
  const float* wsp = w + s * LL;
  const float* ns = nu + s * LL;
  float pu[8], pw[8], pn[8];
  int base = tid * 8;
  {
    float ru = 0, rw = 0, rn = 0;
    #pragma unroll
    for (int e = 0; e < 8; ++e) {
      ru += us[base + e]; pu[e] = ru;
      rw += wsp[base + e]; pw[e] = rw;
      rn += ns[base + e]; pn[e] = rn;
    }
  }
  float tu = pu[7], tw = pw[7], tn = pn[7];
  float iu = tu, iw = tw, in_ = tn;
  #pragma unroll
  for (int off = 1; off < 64; off <<= 1) {
    float a = __shfl_up(iu, off, 64);
    float b = __shfl_up(iw, off, 64);
    float c2 = __shfl_up(in_, off, 64);
    if (l >= off) { iu += a; iw += b; in_ += c2; }
  }
  if (l == 63) { su[wv] = iu; sw[wv] = iw; sn[wv] = in_; }
  __syncthreads();
  float bu = 0, bw = 0, bn = 0;
  for (int i2 = 0; i2 < wv; ++i2) { bu += su[i2]; bw += sw[i2]; bn += sn[i2]; }
  float eu = bu + iu - tu, ew = bw + iw - tw, en = bn + in_ - tn;
  float* os = out + s * LL;
  #pragma unroll
  for (int e = 0; e < 8; ++e) {
    int t = base + e;
    float inv = 1.0f / (float)(t + 1);
    float U = eu + pu[e], W = ew + pw[e], S = en + pn[e];
    os[t] = inv * (0.5f * S + inv * fmaf(0.5f * inv, U, -W));
  }
}

extern "C" void kernel_launch(void* const* d_in, const int* in_sizes, int n_in,
                              void* d_out, int out_size, void* d_ws, size_t ws_size,
                              hipStream_t stream) {
  const float* k = (const float*)d_in[1];
  const float* v = (const float*)d_in[2];
  float* out = (float*)d_out;
  float* ws = (float*)d_ws;
  unsigned short* pref = (unsigned short*)ws;            // BB*NCH*8192 ushorts (4 MB)
  float* nu = ws + (size_t)BB * NCH * 4096;              // after pref (float units)
  float* uu = nu + BB * LL;
  float* ww = uu + BB * LL;
  hipLaunchKernelGGL(k1_mfma, dim3(BB * NCH), dim3(512), 0, stream, k, v, pref);
  hipLaunchKernelGGL(k2_prefix, dim3(BB * 8192 / 256), dim3(256), 0, stream, pref);
  hipLaunchKernelGGL(k3_mfma, dim3(BB * NCH), dim3(512), 0, stream, k, v, pref,
                     uu, ww, nu);
  hipLaunchKernelGGL(k4_out, dim3(BB), dim3(256), 0, stream, uu, ww, nu, out);
}